// Round 1
// baseline (73.870 us; speedup 1.0000x reference)
//
#include <hip/hip_runtime.h>

// SNN binary classifier, fused single kernel.
// B=4096, D=256, H=512, O=2, T=100 (read from d_in[5] at runtime).
// Block = 256 threads handles BM=16 batch rows:
//   Phase 1: h1 = x @ W1^T + b1 into LDS (thread t computes h cols 2t,2t+1
//            for all 16 rows; x rows staged in LDS, broadcast reads).
//   Phase 2: LIF recurrence. 4 waves * 4 rows/wave, 16 lanes/row,
//            32 h-elements per lane in VGPRs. Per-step 16-lane DPP
//            rotate-reduce for the 2-wide fc2 output.

#define BM 16
#define LDS_H_STRIDE 520   // 512 + 8: de-conflicts per-lane h1 reads

template <int CTRL>
__device__ __forceinline__ float dpp_ror_add(float v) {
    // v += rotate-right-within-16-lane-row(v, n); CTRL = 0x120 + n
    int x = __builtin_amdgcn_update_dpp(0, __builtin_bit_cast(int, v),
                                        CTRL, 0xF, 0xF, false);
    return v + __builtin_bit_cast(float, x);
}

__global__ __launch_bounds__(256, 1) void snn_fused_kernel(
    const float* __restrict__ x,   // [4096,256]
    const float* __restrict__ W1,  // [512,256]
    const float* __restrict__ b1,  // [512]
    const float* __restrict__ W2,  // [2,512]
    const float* __restrict__ b2,  // [2]
    const int* __restrict__ tsp,   // [1]
    float* __restrict__ out)       // [4096,2]
{
    __shared__ float xs[BM * 256];            // 16 KiB
    __shared__ float h1s[BM * LDS_H_STRIDE];  // ~32.5 KiB

    const int tid  = threadIdx.x;
    const int row0 = blockIdx.x * BM;

    // ---- stage x rows (coalesced float4) ----
    {
        const float4* xg  = (const float4*)(x + (size_t)row0 * 256);
        float4*       xsv = (float4*)xs;
        #pragma unroll
        for (int i = 0; i < 4; ++i)
            xsv[i * 256 + tid] = xg[i * 256 + tid];
    }
    __syncthreads();

    // ---- Phase 1: h1 for 16 rows x 2 h-columns per thread ----
    {
        const int h0 = tid * 2;
        float acc0[BM], acc1[BM];
        const float bia0 = b1[h0], bia1 = b1[h0 + 1];
        #pragma unroll
        for (int b = 0; b < BM; ++b) { acc0[b] = bia0; acc1[b] = bia1; }

        const float4* w0v = (const float4*)(W1 + (size_t)h0 * 256);
        const float4* w1v = (const float4*)(W1 + (size_t)(h0 + 1) * 256);
        const float4* xsv = (const float4*)xs;

        float4 wa = w0v[0], wb = w1v[0];
        #pragma unroll 1
        for (int k4 = 0; k4 < 64; ++k4) {
            const int kn = (k4 < 63) ? k4 + 1 : 63;   // prefetch next W1 chunk
            float4 wan = w0v[kn], wbn = w1v[kn];
            float4 xv[BM];
            #pragma unroll
            for (int b = 0; b < BM; ++b) xv[b] = xsv[b * 64 + k4]; // broadcast
            #pragma unroll
            for (int b = 0; b < BM; ++b) {
                acc0[b] = fmaf(xv[b].x, wa.x, acc0[b]);
                acc0[b] = fmaf(xv[b].y, wa.y, acc0[b]);
                acc0[b] = fmaf(xv[b].z, wa.z, acc0[b]);
                acc0[b] = fmaf(xv[b].w, wa.w, acc0[b]);
                acc1[b] = fmaf(xv[b].x, wb.x, acc1[b]);
                acc1[b] = fmaf(xv[b].y, wb.y, acc1[b]);
                acc1[b] = fmaf(xv[b].z, wb.z, acc1[b]);
                acc1[b] = fmaf(xv[b].w, wb.w, acc1[b]);
            }
            wa = wan; wb = wbn;
        }
        #pragma unroll
        for (int b = 0; b < BM; ++b) {
            float2* dst = (float2*)&h1s[b * LDS_H_STRIDE + h0];
            *dst = make_float2(acc0[b], acc1[b]);
        }
    }
    __syncthreads();

    // ---- Phase 2: LIF recurrence ----
    {
        const int l       = tid & 63;
        const int w       = tid >> 6;
        const int l15     = l & 15;
        const int b_local = w * 4 + (l >> 4);   // 0..15
        const int row     = row0 + b_local;

        float hv[32], w0r[32], w1r[32], mem[32];
        #pragma unroll
        for (int j = 0; j < 32; ++j) {
            const int h = l15 + j * 16;
            hv[j]  = h1s[b_local * LDS_H_STRIDE + h];
            w0r[j] = W2[h];
            w1r[j] = W2[512 + h];
            mem[j] = 0.0f;
        }
        const float bb0 = b2[0], bb1 = b2[1];
        const int   T   = tsp[0];

        float c0 = 0.0f, c1 = 0.0f;
        for (int t = 0; t < T; ++t) {
            float a0 = 0.0f, a1 = 0.0f, a0b = 0.0f, a1b = 0.0f;
            #pragma unroll
            for (int j = 0; j < 32; j += 2) {
                // membrane update kept non-fused to match reference algebra
                float m0 = __fadd_rn(__fmul_rn(0.9f, mem[j]),     hv[j]);
                float m1 = __fadd_rn(__fmul_rn(0.9f, mem[j + 1]), hv[j + 1]);
                float s0 = (m0 > 1.0f) ? 1.0f : 0.0f;
                float s1 = (m1 > 1.0f) ? 1.0f : 0.0f;
                mem[j]     = m0 - s0;
                mem[j + 1] = m1 - s1;
                a0  = fmaf(s0, w0r[j],     a0);
                a1  = fmaf(s0, w1r[j],     a1);
                a0b = fmaf(s1, w0r[j + 1], a0b);
                a1b = fmaf(s1, w1r[j + 1], a1b);
            }
            a0 += a0b; a1 += a1b;
            // 16-lane rotate-reduce (pure VALU DPP)
            a0 = dpp_ror_add<0x121>(a0); a1 = dpp_ror_add<0x121>(a1);
            a0 = dpp_ror_add<0x122>(a0); a1 = dpp_ror_add<0x122>(a1);
            a0 = dpp_ror_add<0x124>(a0); a1 = dpp_ror_add<0x124>(a1);
            a0 = dpp_ror_add<0x128>(a0); a1 = dpp_ror_add<0x128>(a1);

            c0 += ((a0 + bb0) > 0.0f) ? 1.0f : 0.0f;
            c1 += ((a1 + bb1) > 0.0f) ? 1.0f : 0.0f;
        }

        if (l15 == 0) {
            const float ft = (float)T;
            float2* dst = (float2*)(out + (size_t)row * 2);
            *dst = make_float2(c0 / ft, c1 / ft);
        }
    }
}

extern "C" void kernel_launch(void* const* d_in, const int* in_sizes, int n_in,
                              void* d_out, int out_size, void* d_ws, size_t ws_size,
                              hipStream_t stream) {
    const float* x   = (const float*)d_in[0];
    const float* W1  = (const float*)d_in[1];
    const float* b1  = (const float*)d_in[2];
    const float* W2  = (const float*)d_in[3];
    const float* b2  = (const float*)d_in[4];
    const int*   tsp = (const int*)d_in[5];
    float*       out = (float*)d_out;

    const int B = in_sizes[0] / 256;          // 4096
    snn_fused_kernel<<<dim3(B / BM), dim3(256), 0, stream>>>(
        x, W1, b1, W2, b2, tsp, out);
}